// Round 1
// baseline (6293.774 us; speedup 1.0000x reference)
//
#include <hip/hip_runtime.h>
#include <math.h>

#define N 4
#define C 256
#define H 128
#define W 128
#define CO 288        // GROUP * K * K = 32 * 9
#define OH 126
#define OW 126
#define GROUP 32
#define CPG 8         // channels per group (256/32)
#define EPS 1e-5f

#define HW (OH*OW)          // 15876
#define XSLICE (H*W)        // 16384
#define XNSTRIDE (C*H*W)    // 4194304
#define SNSTRIDE (CO*HW)    // 4572288
#define LONSTRIDE (C*HW)    // 4064256

// ---------------- Conv 3x3 VALID, fp32 direct, weights in LDS ----------------
__global__ __launch_bounds__(256) void conv_kernel(const float* __restrict__ x,
                                                   const float* __restrict__ wgt,
                                                   float* __restrict__ sigma) {
    __shared__ float lw[C * 9]; // 2304 floats = 9216 B
    const int co = blockIdx.y;
    const int n  = blockIdx.z;
    for (int i = threadIdx.x; i < C * 9; i += 256)
        lw[i] = wgt[(size_t)co * (C * 9) + i];
    __syncthreads();

    const int pos = blockIdx.x * 256 + threadIdx.x;
    if (pos >= HW) return;
    const int oh = pos / OW;
    const int ow = pos - oh * OW;

    const float* xp = x + (size_t)n * XNSTRIDE + oh * W + ow;
    float acc = 0.f;
    #pragma unroll 4
    for (int ci = 0; ci < C; ++ci) {
        const float* wp = &lw[ci * 9];
        const float* xr = xp + (size_t)ci * XSLICE;
        float a0 = xr[0],     a1 = xr[1],     a2 = xr[2];
        float a3 = xr[W],     a4 = xr[W+1],   a5 = xr[W+2];
        float a6 = xr[2*W],   a7 = xr[2*W+1], a8 = xr[2*W+2];
        acc += a0*wp[0] + a1*wp[1] + a2*wp[2]
             + a3*wp[3] + a4*wp[4] + a5*wp[5]
             + a6*wp[6] + a7*wp[7] + a8*wp[8];
    }
    sigma[(size_t)n * SNSTRIDE + (size_t)co * HW + pos] = acc;
}

// ---------------- Per-channel mean/var over (N, OH, OW) ----------------
// coef[c]      = gamma[c] * rsqrt(var+eps)
// coef[CO + c] = beta[c] - mean * coef[c]
__global__ __launch_bounds__(256) void stats_kernel(const float* __restrict__ sigma,
                                                    const float* __restrict__ gamma,
                                                    const float* __restrict__ beta,
                                                    float* __restrict__ coef) {
    const int c = blockIdx.x;
    float sum = 0.f, sq = 0.f;
    for (int n = 0; n < N; ++n) {
        const float* sp = sigma + (size_t)n * SNSTRIDE + (size_t)c * HW;
        for (int i = threadIdx.x; i < HW; i += 256) {
            float v = sp[i];
            sum += v; sq += v * v;
        }
    }
    // wave reduce (width 64)
    for (int off = 32; off > 0; off >>= 1) {
        sum += __shfl_down(sum, off, 64);
        sq  += __shfl_down(sq,  off, 64);
    }
    __shared__ float ls[4], lq[4];
    const int wid = threadIdx.x >> 6, lane = threadIdx.x & 63;
    if (lane == 0) { ls[wid] = sum; lq[wid] = sq; }
    __syncthreads();
    if (threadIdx.x == 0) {
        float S = ls[0] + ls[1] + ls[2] + ls[3];
        float Q = lq[0] + lq[1] + lq[2] + lq[3];
        const float cnt = (float)(N * HW);
        float mean = S / cnt;
        float var  = Q / cnt - mean * mean;
        float a = gamma[c] * rsqrtf(var + EPS);
        coef[c]      = a;
        coef[CO + c] = beta[c] - mean * a;
    }
}

// ---------------- Fused normalize + softmax(288) + grouped dynamic 3x3 ----------------
// One thread per lo-res position (n, oh, ow). Writes out_lo (N, C, OH, OW).
__global__ __launch_bounds__(256) void fuse_kernel(const float* __restrict__ x,
                                                   const float* __restrict__ sigma,
                                                   const float* __restrict__ coef,
                                                   float* __restrict__ outlo) {
    __shared__ float a[CO], b[CO];
    for (int i = threadIdx.x; i < CO; i += 256) {
        a[i] = coef[i];
        b[i] = coef[CO + i];
    }
    __syncthreads();

    const int gpos = blockIdx.x * 256 + threadIdx.x;
    if (gpos >= N * HW) return;
    const int n  = gpos / HW;
    const int hw = gpos - n * HW;
    const int oh = hw / OW;
    const int ow = hw - oh * OW;

    const float* sp = sigma + (size_t)n * SNSTRIDE + hw;

    // pass 1: max logit
    float mx = -1e30f;
    for (int ch = 0; ch < CO; ++ch) {
        float s = sp[(size_t)ch * HW] * a[ch] + b[ch];
        mx = fmaxf(mx, s);
    }
    // pass 2: sum of exp
    float sum = 0.f;
    for (int ch = 0; ch < CO; ++ch) {
        float s = sp[(size_t)ch * HW] * a[ch] + b[ch];
        sum += __expf(s - mx);
    }
    const float inv = 1.f / sum;

    const float* xb = x + (size_t)n * XNSTRIDE + oh * W + ow;
    float* ob = outlo + (size_t)n * LONSTRIDE + hw;

    for (int g = 0; g < GROUP; ++g) {
        float acc[CPG];
        #pragma unroll
        for (int c = 0; c < CPG; ++c) acc[c] = 0.f;
        #pragma unroll
        for (int p = 0; p < 9; ++p) {
            const int ch = g * 9 + p;
            float s = sp[(size_t)ch * HW] * a[ch] + b[ch];
            float wv = __expf(s - mx) * inv;
            const float* xr = xb + (size_t)(g * CPG) * XSLICE + (p / 3) * W + (p % 3);
            #pragma unroll
            for (int c = 0; c < CPG; ++c)
                acc[c] += xr[(size_t)c * XSLICE] * wv;
        }
        #pragma unroll
        for (int c = 0; c < CPG; ++c)
            ob[(size_t)(g * CPG + c) * HW] = acc[c];
    }
}

// ---------------- Bilinear align-corners upsample 126 -> 128 ----------------
__global__ __launch_bounds__(256) void upsample_kernel(const float* __restrict__ lo,
                                                       float* __restrict__ out) {
    const int idx = blockIdx.x * 256 + threadIdx.x; // N*C*H*W = 16777216
    const int xi = idx & (W - 1);
    const int yi = (idx >> 7) & (H - 1);
    const int nc = idx >> 14;

    const float scale = 125.0f / 127.0f;
    const float sy = yi * scale;
    const float sx = xi * scale;
    int y0 = (int)sy;
    int x0 = (int)sx;
    float wy = sy - (float)y0;
    float wx = sx - (float)x0;
    int y1 = min(y0 + 1, OH - 1);
    int x1 = min(x0 + 1, OW - 1);

    const float* p = lo + (size_t)nc * HW;
    float v00 = p[y0 * OW + x0], v01 = p[y0 * OW + x1];
    float v10 = p[y1 * OW + x0], v11 = p[y1 * OW + x1];
    float top = v00 * (1.f - wx) + v01 * wx;
    float bot = v10 * (1.f - wx) + v11 * wx;
    out[idx] = top * (1.f - wy) + bot * wy;
}

extern "C" void kernel_launch(void* const* d_in, const int* in_sizes, int n_in,
                              void* d_out, int out_size, void* d_ws, size_t ws_size,
                              hipStream_t stream) {
    const float* x      = (const float*)d_in[0];
    const float* conv_w = (const float*)d_in[1];
    const float* gamma  = (const float*)d_in[2];
    const float* beta   = (const float*)d_in[3];
    float* out = (float*)d_out;
    float* ws  = (float*)d_ws;

    // workspace layout (floats):
    //   sigma : [0, 18289152)                      = N*CO*OH*OW
    //   coef  : [18289152, 18289152+576)           = 2*CO (padded to 1024)
    //   outlo : [18290176, 18290176+16257024)      = N*C*OH*OW
    float* sigma = ws;
    float* coef  = ws + 18289152;
    float* outlo = ws + 18290176;

    dim3 cgrid((HW + 255) / 256, CO, N); // (63, 288, 4)
    conv_kernel<<<cgrid, 256, 0, stream>>>(x, conv_w, sigma);

    stats_kernel<<<CO, 256, 0, stream>>>(sigma, gamma, beta, coef);

    fuse_kernel<<<(N * HW + 255) / 256, 256, 0, stream>>>(x, sigma, coef, outlo);

    upsample_kernel<<<(N * C * H * W) / 256, 256, 0, stream>>>(outlo, out);
}

// Round 2
// 3055.844 us; speedup vs baseline: 2.0596x; 2.0596x over previous
//
#include <hip/hip_runtime.h>
#include <math.h>

#define N 4
#define C 256
#define H 128
#define W 128
#define CO 288        // GROUP * K * K = 32 * 9
#define OH 126
#define OW 126
#define GROUP 32
#define CPG 8         // channels per group (256/32)
#define EPS 1e-5f

#define HW (OH*OW)          // 15876
#define XSLICE (H*W)        // 16384
#define XNSTRIDE (C*H*W)    // 4194304
#define SNSTRIDE (CO*HW)    // 4572288
#define LONSTRIDE (C*HW)    // 4064256

// conv tiling
#define TW 64     // output positions (cols) per block
#define PG 8      // positions per thread
#define CG 9      // output channels per thread
#define CICH 2    // input channels staged per chunk

// ---------------- Conv 3x3 VALID, fp32 register-blocked, x+w in LDS ----------------
// Grid: (2, OH, N). Block: 256 = 8 pos-groups x 32 co-groups.
// Each block: 64 positions x all 288 co. Thread: 8 pos x 9 co = 72 acc.
__global__ __launch_bounds__(256) void conv_kernel(const float* __restrict__ x,
                                                   const float* __restrict__ wgt,
                                                   float* __restrict__ sigma) {
    __shared__ float wlds[CICH][CO][9];   // 2*288*9*4 = 20736 B
    __shared__ float xlds[CICH][3][68];   // 2*3*68*4  = 1632 B

    const int tid = threadIdx.x;
    const int pg  = tid >> 5;   // 0..7
    const int cg  = tid & 31;   // 0..31
    const int ow0 = blockIdx.x * TW;
    const int oh  = blockIdx.y;
    const int n   = blockIdx.z;

    const int maxc = (ow0 + 66 <= W) ? 66 : (W - ow0); // available halo cols

    float acc[CG][PG];
    #pragma unroll
    for (int j = 0; j < CG; ++j)
        #pragma unroll
        for (int p = 0; p < PG; ++p) acc[j][p] = 0.f;

    const float* xbase = x + (size_t)n * XNSTRIDE + (size_t)oh * W + ow0;

    for (int ci0 = 0; ci0 < C; ci0 += CICH) {
        __syncthreads();
        // stage weights: for each co, 18 contiguous floats (ci0, ci0+1)
        for (int i = tid; i < CICH * CO * 9; i += 256) {
            int co = i / (CICH * 9);
            int r  = i - co * (CICH * 9);
            int cil = r / 9;
            int j   = r - cil * 9;
            wlds[cil][co][j] = wgt[(size_t)co * (C * 9) + (size_t)ci0 * 9 + r];
        }
        // stage x: CICH channels x 3 rows x up-to-66 cols
        for (int i = tid; i < CICH * 3 * 66; i += 256) {
            int cil = i / 198;
            int rr  = i - cil * 198;
            int r   = rr / 66;
            int cc  = rr - r * 66;
            if (cc < maxc)
                xlds[cil][r][cc] = xbase[(size_t)(ci0 + cil) * XSLICE + r * W + cc];
        }
        __syncthreads();

        #pragma unroll
        for (int cil = 0; cil < CICH; ++cil) {
            float xv[3][10];
            #pragma unroll
            for (int r = 0; r < 3; ++r)
                #pragma unroll
                for (int c = 0; c < 10; ++c)
                    xv[r][c] = xlds[cil][r][pg * 8 + c];
            const float* wrow = &wlds[cil][cg * 9][0];
            #pragma unroll
            for (int j = 0; j < CG; ++j) {
                float wv[9];
                #pragma unroll
                for (int k = 0; k < 9; ++k) wv[k] = wrow[j * 9 + k];
                #pragma unroll
                for (int p = 0; p < PG; ++p) {
                    float s = acc[j][p];
                    s += xv[0][p  ] * wv[0] + xv[0][p+1] * wv[1] + xv[0][p+2] * wv[2]
                       + xv[1][p  ] * wv[3] + xv[1][p+1] * wv[4] + xv[1][p+2] * wv[5]
                       + xv[2][p  ] * wv[6] + xv[2][p+1] * wv[7] + xv[2][p+2] * wv[8];
                    acc[j][p] = s;
                }
            }
        }
    }

    // store: co = cg*9+j, ow = ow0 + pg*8 + p
    float* sb = sigma + (size_t)n * SNSTRIDE + (size_t)oh * OW + ow0 + pg * 8;
    #pragma unroll
    for (int j = 0; j < CG; ++j) {
        const size_t co = (size_t)(cg * 9 + j);
        #pragma unroll
        for (int p = 0; p < PG; ++p) {
            int ow = ow0 + pg * 8 + p;
            if (ow < OW) sb[co * HW + p] = acc[j][p];
        }
    }
}

// ---------------- Per-channel mean/var over (N, OH, OW) ----------------
__global__ __launch_bounds__(256) void stats_kernel(const float* __restrict__ sigma,
                                                    const float* __restrict__ gamma,
                                                    const float* __restrict__ beta,
                                                    float* __restrict__ coef) {
    const int c = blockIdx.x;
    float sum = 0.f, sq = 0.f;
    for (int n = 0; n < N; ++n) {
        const float* sp = sigma + (size_t)n * SNSTRIDE + (size_t)c * HW;
        for (int i = threadIdx.x; i < HW; i += 256) {
            float v = sp[i];
            sum += v; sq += v * v;
        }
    }
    for (int off = 32; off > 0; off >>= 1) {
        sum += __shfl_down(sum, off, 64);
        sq  += __shfl_down(sq,  off, 64);
    }
    __shared__ float ls[4], lq[4];
    const int wid = threadIdx.x >> 6, lane = threadIdx.x & 63;
    if (lane == 0) { ls[wid] = sum; lq[wid] = sq; }
    __syncthreads();
    if (threadIdx.x == 0) {
        float S = ls[0] + ls[1] + ls[2] + ls[3];
        float Q = lq[0] + lq[1] + lq[2] + lq[3];
        const float cnt = (float)(N * HW);
        float mean = S / cnt;
        float var  = Q / cnt - mean * mean;
        float a = gamma[c] * rsqrtf(var + EPS);
        coef[c]      = a;
        coef[CO + c] = beta[c] - mean * a;
    }
}

// ---------------- Fused normalize + softmax(288) + grouped dynamic 3x3 ----------------
__global__ __launch_bounds__(256) void fuse_kernel(const float* __restrict__ x,
                                                   const float* __restrict__ sigma,
                                                   const float* __restrict__ coef,
                                                   float* __restrict__ outlo) {
    __shared__ float a[CO], b[CO];
    for (int i = threadIdx.x; i < CO; i += 256) {
        a[i] = coef[i];
        b[i] = coef[CO + i];
    }
    __syncthreads();

    const int gpos = blockIdx.x * 256 + threadIdx.x;
    if (gpos >= N * HW) return;
    const int n  = gpos / HW;
    const int hw = gpos - n * HW;
    const int oh = hw / OW;
    const int ow = hw - oh * OW;

    const float* sp = sigma + (size_t)n * SNSTRIDE + hw;

    float mx = -1e30f;
    for (int ch = 0; ch < CO; ++ch) {
        float s = sp[(size_t)ch * HW] * a[ch] + b[ch];
        mx = fmaxf(mx, s);
    }
    float sum = 0.f;
    for (int ch = 0; ch < CO; ++ch) {
        float s = sp[(size_t)ch * HW] * a[ch] + b[ch];
        sum += __expf(s - mx);
    }
    const float inv = 1.f / sum;

    const float* xb = x + (size_t)n * XNSTRIDE + oh * W + ow;
    float* ob = outlo + (size_t)n * LONSTRIDE + hw;

    for (int g = 0; g < GROUP; ++g) {
        float acc[CPG];
        #pragma unroll
        for (int c = 0; c < CPG; ++c) acc[c] = 0.f;
        #pragma unroll
        for (int p = 0; p < 9; ++p) {
            const int ch = g * 9 + p;
            float s = sp[(size_t)ch * HW] * a[ch] + b[ch];
            float wv = __expf(s - mx) * inv;
            const float* xr = xb + (size_t)(g * CPG) * XSLICE + (p / 3) * W + (p % 3);
            #pragma unroll
            for (int c = 0; c < CPG; ++c)
                acc[c] += xr[(size_t)c * XSLICE] * wv;
        }
        #pragma unroll
        for (int c = 0; c < CPG; ++c)
            ob[(size_t)(g * CPG + c) * HW] = acc[c];
    }
}

// ---------------- Bilinear align-corners upsample 126 -> 128 ----------------
__global__ __launch_bounds__(256) void upsample_kernel(const float* __restrict__ lo,
                                                       float* __restrict__ out) {
    const int idx = blockIdx.x * 256 + threadIdx.x;
    const int xi = idx & (W - 1);
    const int yi = (idx >> 7) & (H - 1);
    const int nc = idx >> 14;

    const float scale = 125.0f / 127.0f;
    const float sy = yi * scale;
    const float sx = xi * scale;
    int y0 = (int)sy;
    int x0 = (int)sx;
    float wy = sy - (float)y0;
    float wx = sx - (float)x0;
    int y1 = min(y0 + 1, OH - 1);
    int x1 = min(x0 + 1, OW - 1);

    const float* p = lo + (size_t)nc * HW;
    float v00 = p[y0 * OW + x0], v01 = p[y0 * OW + x1];
    float v10 = p[y1 * OW + x0], v11 = p[y1 * OW + x1];
    float top = v00 * (1.f - wx) + v01 * wx;
    float bot = v10 * (1.f - wx) + v11 * wx;
    out[idx] = top * (1.f - wy) + bot * wy;
}

extern "C" void kernel_launch(void* const* d_in, const int* in_sizes, int n_in,
                              void* d_out, int out_size, void* d_ws, size_t ws_size,
                              hipStream_t stream) {
    const float* x      = (const float*)d_in[0];
    const float* conv_w = (const float*)d_in[1];
    const float* gamma  = (const float*)d_in[2];
    const float* beta   = (const float*)d_in[3];
    float* out = (float*)d_out;
    float* ws  = (float*)d_ws;

    float* sigma = ws;                 // N*CO*OH*OW = 18289152 floats
    float* coef  = ws + 18289152;      // 2*CO (padded to 1024)
    float* outlo = ws + 18290176;      // N*C*OH*OW = 16257024 floats

    dim3 cgrid(2, OH, N); // (2, 126, 4) = 1008 blocks
    conv_kernel<<<cgrid, 256, 0, stream>>>(x, conv_w, sigma);

    stats_kernel<<<CO, 256, 0, stream>>>(sigma, gamma, beta, coef);

    fuse_kernel<<<(N * HW + 255) / 256, 256, 0, stream>>>(x, sigma, coef, outlo);

    upsample_kernel<<<(N * C * H * W) / 256, 256, 0, stream>>>(outlo, out);
}

// Round 3
// 1004.432 us; speedup vs baseline: 6.2660x; 3.0424x over previous
//
#include <hip/hip_runtime.h>
#include <hip/hip_bf16.h>
#include <math.h>

#define N 4
#define C 256
#define H 128
#define W 128
#define CO 288        // GROUP * K * K = 32 * 9
#define OH 126
#define OW 126
#define GROUP 32
#define CPG 8
#define EPS 1e-5f

#define HW (OH*OW)          // 15876
#define XSLICE (H*W)        // 16384
#define XNSTRIDE (C*H*W)    // 4194304
#define SNSTRIDE (CO*HW)    // 4572288
#define LONSTRIDE (C*HW)    // 4064256

typedef unsigned short u16;
typedef __attribute__((ext_vector_type(8))) short short8;
typedef __attribute__((ext_vector_type(4))) float float4v;

__device__ inline u16 f2bf(float v) {
    __hip_bfloat16 b = __float2bfloat16(v);
    return __builtin_bit_cast(u16, b);
}
__device__ inline float bf2f(u16 u) {
    __hip_bfloat16 b = __builtin_bit_cast(__hip_bfloat16, u);
    return __bfloat162float(b);
}

// ---------------- Prep: split x into bf16 hi/lo, transpose to NHWC ----------------
// xh/xl layout: [n][h][w][ci] (ci contiguous)
__global__ __launch_bounds__(256) void split_x_kernel(const float* __restrict__ x,
                                                      u16* __restrict__ xh,
                                                      u16* __restrict__ xl) {
    const int ci = threadIdx.x;          // 0..255
    const int w0 = blockIdx.x * 8;       // 16 groups
    const int h  = blockIdx.y;
    const int n  = blockIdx.z;
    const float* src = x + ((size_t)(n*C + ci)*H + h)*W + w0;
    float4 v0 = *(const float4*)src;
    float4 v1 = *(const float4*)(src + 4);
    float vals[8] = {v0.x, v0.y, v0.z, v0.w, v1.x, v1.y, v1.z, v1.w};
    size_t obase = ((size_t)(n*H + h)*W + w0)*C + ci;
    #pragma unroll
    for (int dw = 0; dw < 8; ++dw) {
        float v = vals[dw];
        u16 hb = f2bf(v);
        xh[obase + (size_t)dw*C] = hb;
        xl[obase + (size_t)dw*C] = f2bf(v - bf2f(hb));
    }
}

// ---------------- Prep: split w into bf16 hi/lo, layout [s][co][ci] ----------------
__global__ __launch_bounds__(256) void split_w_kernel(const float* __restrict__ wgt,
                                                      u16* __restrict__ whT,
                                                      u16* __restrict__ wlT) {
    const int i = blockIdx.x*256 + threadIdx.x;  // < 9*288*256 = 663552
    const int ci = i & 255;
    const int co = (i >> 8) % CO;
    const int s  = i / (CO*256);
    float v = wgt[(size_t)co*(C*9) + (size_t)ci*9 + s];
    u16 hb = f2bf(v);
    whT[i] = hb;
    wlT[i] = f2bf(v - bf2f(hb));
}

// ---------------- Conv 3x3 VALID via bf16 MFMA implicit GEMM ----------------
// Grid (2, OH, N), block 256 = 4 waves.
// Block: 64 output positions (one row) x all 288 co. Wave w: pos [16w,16w+16) x 288.
// K-loop: 8 ci-chunks of 32 x 9 shifts x 3 hi/lo products.
__global__ __launch_bounds__(256) void conv_mfma_kernel(const u16* __restrict__ xh,
                                                        const u16* __restrict__ xl,
                                                        const u16* __restrict__ whT,
                                                        const u16* __restrict__ wlT,
                                                        float* __restrict__ sigma) {
    __shared__ __align__(16) u16 xs[2][3][72][32];   // split, row, col, ci : 27648 B
    __shared__ __align__(16) u16 wsh[2][288][32];    // split, co, ci      : 36864 B

    const int tid  = threadIdx.x;
    const int wave = tid >> 6;
    const int lane = tid & 63;
    const int m16  = lane & 15;
    const int q    = lane >> 4;
    const int ow0  = blockIdx.x * 64;
    const int oh   = blockIdx.y;
    const int n    = blockIdx.z;

    float4v acc[18];
    #pragma unroll
    for (int j = 0; j < 18; ++j) acc[j] = (float4v)(0.f);

    for (int ci0 = 0; ci0 < C; ci0 += 32) {
        __syncthreads();
        // stage x tile: slots quad(4) x col(72) x row(3) x split(2) = 1728 x 16B
        for (int i = tid; i < 1728; i += 256) {
            const int quad = i & 3;
            const int t    = i >> 2;       // 0..431
            const int col  = t % 72;
            const int rs   = t / 72;       // 0..5
            const int row  = rs % 3;
            const int sp   = rs / 3;
            if (ow0 + col < W) {
                const u16* src = (sp ? xl : xh)
                    + (((size_t)(n*H + oh + row)*W + ow0 + col)*C + ci0 + quad*8);
                *(uint4*)&xs[sp][row][col][quad*8] = *(const uint4*)src;
            }
        }
        for (int s = 0; s < 9; ++s) {
            const int ky = s / 3, kx = s - 3*ky;
            __syncthreads();   // prev compute done (wsh reuse) + xs visible
            // stage w[s]: slots quad(4) x co(288) x split(2) = 2304 x 16B
            for (int i = tid; i < 2304; i += 256) {
                const int quad = i & 3;
                const int t    = i >> 2;
                const int co   = t % 288;
                const int sp   = t / 288;
                const u16* src = (sp ? wlT : whT)
                    + ((size_t)s*(CO*256) + (size_t)co*256 + ci0 + quad*8);
                *(uint4*)&wsh[sp][co][quad*8] = *(const uint4*)src;
            }
            __syncthreads();

            short8 ah = *(const short8*)&xs[0][ky][wave*16 + m16 + kx][q*8];
            short8 al = *(const short8*)&xs[1][ky][wave*16 + m16 + kx][q*8];
            #pragma unroll
            for (int j = 0; j < 18; ++j) {
                short8 bh = *(const short8*)&wsh[0][j*16 + m16][q*8];
                short8 bl = *(const short8*)&wsh[1][j*16 + m16][q*8];
                acc[j] = __builtin_amdgcn_mfma_f32_16x16x32_bf16(ah, bh, acc[j], 0, 0, 0);
                acc[j] = __builtin_amdgcn_mfma_f32_16x16x32_bf16(al, bh, acc[j], 0, 0, 0);
                acc[j] = __builtin_amdgcn_mfma_f32_16x16x32_bf16(ah, bl, acc[j], 0, 0, 0);
            }
        }
    }

    // store: D[row=q*4+r][col=m16] -> pos = wave*16+q*4+r, co = j*16+m16
    const int posb = wave*16 + q*4;
    #pragma unroll
    for (int j = 0; j < 18; ++j) {
        const int co = j*16 + m16;
        float* dst = sigma + (size_t)n*SNSTRIDE + (size_t)co*HW + oh*OW;
        #pragma unroll
        for (int r = 0; r < 4; ++r) {
            const int ow = ow0 + posb + r;
            if (ow < OW) dst[ow] = acc[j][r];
        }
    }
}

// ---------------- Per-channel mean/var over (N, OH, OW) ----------------
__global__ __launch_bounds__(1024) void stats_kernel(const float* __restrict__ sigma,
                                                     const float* __restrict__ gamma,
                                                     const float* __restrict__ beta,
                                                     float* __restrict__ coef) {
    const int c = blockIdx.x;
    float sum = 0.f, sq = 0.f;
    for (int n = 0; n < N; ++n) {
        const float* sp = sigma + (size_t)n*SNSTRIDE + (size_t)c*HW;
        for (int i = threadIdx.x; i < HW; i += 1024) {
            float v = sp[i];
            sum += v; sq += v * v;
        }
    }
    for (int off = 32; off > 0; off >>= 1) {
        sum += __shfl_down(sum, off, 64);
        sq  += __shfl_down(sq,  off, 64);
    }
    __shared__ float ls[16], lq[16];
    const int wid = threadIdx.x >> 6, lane = threadIdx.x & 63;
    if (lane == 0) { ls[wid] = sum; lq[wid] = sq; }
    __syncthreads();
    if (threadIdx.x == 0) {
        float S = 0.f, Q = 0.f;
        #pragma unroll
        for (int i = 0; i < 16; ++i) { S += ls[i]; Q += lq[i]; }
        const float cnt = (float)(N * HW);
        float mean = S / cnt;
        float var  = Q / cnt - mean * mean;
        float a = gamma[c] * rsqrtf(var + EPS);
        coef[c]      = a;
        coef[CO + c] = beta[c] - mean * a;
    }
}

// ---------------- Fused normalize + softmax(288) + grouped dynamic 3x3 ----------------
__global__ __launch_bounds__(256) void fuse_kernel(const float* __restrict__ x,
                                                   const float* __restrict__ sigma,
                                                   const float* __restrict__ coef,
                                                   float* __restrict__ outlo) {
    __shared__ float a[CO], b[CO];
    for (int i = threadIdx.x; i < CO; i += 256) {
        a[i] = coef[i];
        b[i] = coef[CO + i];
    }
    __syncthreads();

    const int gpos = blockIdx.x * 256 + threadIdx.x;
    if (gpos >= N * HW) return;
    const int n  = gpos / HW;
    const int hw = gpos - n * HW;
    const int oh = hw / OW;
    const int ow = hw - oh * OW;

    const float* sp = sigma + (size_t)n * SNSTRIDE + hw;

    float mx = -1e30f;
    for (int ch = 0; ch < CO; ++ch) {
        float s = sp[(size_t)ch * HW] * a[ch] + b[ch];
        mx = fmaxf(mx, s);
    }
    float sum = 0.f;
    for (int ch = 0; ch < CO; ++ch) {
        float s = sp[(size_t)ch * HW] * a[ch] + b[ch];
        sum += __expf(s - mx);
    }
    const float inv = 1.f / sum;

    const float* xb = x + (size_t)n * XNSTRIDE + oh * W + ow;
    float* ob = outlo + (size_t)n * LONSTRIDE + hw;

    for (int g = 0; g < GROUP; ++g) {
        float acc[CPG];
        #pragma unroll
        for (int c = 0; c < CPG; ++c) acc[c] = 0.f;
        #pragma unroll
        for (int p = 0; p < 9; ++p) {
            const int ch = g * 9 + p;
            float s = sp[(size_t)ch * HW] * a[ch] + b[ch];
            float wv = __expf(s - mx) * inv;
            const float* xr = xb + (size_t)(g * CPG) * XSLICE + (p / 3) * W + (p % 3);
            #pragma unroll
            for (int c = 0; c < CPG; ++c)
                acc[c] += xr[(size_t)c * XSLICE] * wv;
        }
        #pragma unroll
        for (int c = 0; c < CPG; ++c)
            ob[(size_t)(g * CPG + c) * HW] = acc[c];
    }
}

// ---------------- Bilinear align-corners upsample 126 -> 128 ----------------
__global__ __launch_bounds__(256) void upsample_kernel(const float* __restrict__ lo,
                                                       float* __restrict__ out) {
    const int idx = blockIdx.x * 256 + threadIdx.x;
    const int xi = idx & (W - 1);
    const int yi = (idx >> 7) & (H - 1);
    const int nc = idx >> 14;

    const float scale = 125.0f / 127.0f;
    const float sy = yi * scale;
    const float sx = xi * scale;
    int y0 = (int)sy;
    int x0 = (int)sx;
    float wy = sy - (float)y0;
    float wx = sx - (float)x0;
    int y1 = min(y0 + 1, OH - 1);
    int x1 = min(x0 + 1, OW - 1);

    const float* p = lo + (size_t)nc * HW;
    float v00 = p[y0 * OW + x0], v01 = p[y0 * OW + x1];
    float v10 = p[y1 * OW + x0], v11 = p[y1 * OW + x1];
    float top = v00 * (1.f - wx) + v01 * wx;
    float bot = v10 * (1.f - wx) + v11 * wx;
    out[idx] = top * (1.f - wy) + bot * wy;
}

extern "C" void kernel_launch(void* const* d_in, const int* in_sizes, int n_in,
                              void* d_out, int out_size, void* d_ws, size_t ws_size,
                              hipStream_t stream) {
    const float* x      = (const float*)d_in[0];
    const float* conv_w = (const float*)d_in[1];
    const float* gamma  = (const float*)d_in[2];
    const float* beta   = (const float*)d_in[3];
    float* out = (float*)d_out;
    float* ws  = (float*)d_ws;

    // workspace (floats):
    //   sigma : [0, 18289152)
    //   coef  : [18289152, +1024)
    //   outlo : [18290176, +16257024)   -- ALIASED with xh/xl (prep+conv finish first)
    float* sigma = ws;
    float* coef  = ws + 18289152;
    float* outlo = ws + 18290176;
    u16* xhp = (u16*)(ws + 18290176);               // 16777216 u16 = 33.5 MB
    u16* xlp = xhp + (size_t)N*H*W*C;               // 16777216 u16
    u16* whT = xlp + (size_t)N*H*W*C;               // 663552 u16
    u16* wlT = whT + (size_t)9*CO*256;              // 663552 u16
    // total ws usage ~143 MB

    split_x_kernel<<<dim3(16, 128, 4), 256, 0, stream>>>(x, xhp, xlp);
    split_w_kernel<<<(9*CO*256)/256, 256, 0, stream>>>(conv_w, whT, wlT);

    conv_mfma_kernel<<<dim3(2, OH, N), 256, 0, stream>>>(xhp, xlp, whT, wlT, sigma);

    stats_kernel<<<CO, 1024, 0, stream>>>(sigma, gamma, beta, coef);

    fuse_kernel<<<(N * HW + 255) / 256, 256, 0, stream>>>(x, sigma, coef, outlo);

    upsample_kernel<<<(N * C * H * W) / 256, 256, 0, stream>>>(outlo, out);
}